// Round 8
// baseline (261.065 us; speedup 1.0000x reference)
//
#include <hip/hip_runtime.h>

typedef __attribute__((ext_vector_type(4))) float f32x4;
typedef __attribute__((ext_vector_type(8))) short bf16x8;

__device__ __forceinline__ unsigned short f2b(float f) {
  unsigned u = __float_as_uint(f);
  u = (u + 0x7FFFu + ((u >> 16) & 1u)) >> 16;
  return (unsigned short)u;
}

#define BAR() asm volatile("s_barrier" ::: "memory")
#define VMCNT(N) asm volatile("s_waitcnt vmcnt(" #N ")" ::: "memory")
#define SBAR0() __builtin_amdgcn_sched_barrier(0)

// ---------------- K1: selector + skill-mix of LoRA params ----------------
__global__ void combine_kernel(const float* __restrict__ logits,   // [32][8]
                               const int*   __restrict__ tasks,    // [8]
                               const float* __restrict__ A,        // [8][2048][16]
                               const float* __restrict__ B,        // [8][16][2048]
                               unsigned short* __restrict__ Art,   // [8][16][2048]
                               unsigned short* __restrict__ Brt)   // [8][2048][16]
{
  int idx = blockIdx.x * 256 + threadIdx.x;
  int b = idx >> 11;
  int i = idx & 2047;
  if (b >= 8) return;
  int task = tasks[b];
  float p[8]; float s = 0.f;
  #pragma unroll
  for (int t = 0; t < 8; ++t) {
    float l = logits[task * 8 + t];
    float e = 1.f / (1.f + __expf(-l));
    p[t] = e; s += e;
  }
  float inv = 1.f / (s + 1e-12f);
  #pragma unroll
  for (int t = 0; t < 8; ++t) p[t] *= inv;

  float ar[16];
  #pragma unroll
  for (int r = 0; r < 16; ++r) ar[r] = 0.f;
  for (int t = 0; t < 8; ++t) {
    const float* ap = A + ((size_t)t * 2048 + i) * 16;
    float pt = p[t];
    #pragma unroll
    for (int r = 0; r < 16; ++r) ar[r] += pt * ap[r];
  }
  #pragma unroll
  for (int r = 0; r < 16; ++r)
    Art[((size_t)b * 16 + r) * 2048 + i] = f2b(ar[r]);

  float br[16];
  #pragma unroll
  for (int r = 0; r < 16; ++r) br[r] = 0.f;
  for (int t = 0; t < 8; ++t) {
    float pt = p[t];
    #pragma unroll
    for (int r = 0; r < 16; ++r) br[r] += pt * B[((size_t)t * 16 + r) * 2048 + i];
  }
  #pragma unroll
  for (int r = 0; r < 16; ++r)
    Brt[((size_t)b * 2048 + i) * 16 + r] = f2b(br[r] * 0.0625f);
}

// ---------------- K2: prep = {x f32->bf16 + xa = x@A_mix} ∪ {W f32->bf16} ----------------
__global__ void prep_kernel(const float* __restrict__ x,            // [16384][2048]
                            const unsigned short* __restrict__ Art, // [8][16][2048]
                            const float* __restrict__ W,            // [2048][2048]
                            unsigned short* __restrict__ Wb,        // [2048][2048]
                            unsigned short* __restrict__ xb,        // [16384][2048]
                            unsigned short* __restrict__ xa)        // [16384][16]
{
  __shared__ float red[4][16][16];
  int blk = blockIdx.x;
  int tid = threadIdx.x;
  if (blk >= 1024) {
    int idx0 = (blk - 1024) * 256 + tid;
    #pragma unroll
    for (int c = 0; c < 32; ++c) {
      size_t i = ((size_t)idx0 + (size_t)c * 32768) * 4;
      f32x4 v = *(const f32x4*)(W + i);
      ushort4 o;
      o.x = f2b(v.x); o.y = f2b(v.y); o.z = f2b(v.z); o.w = f2b(v.w);
      *(ushort4*)(Wb + i) = o;
    }
    return;
  }
  int lane = tid & 63, wv = tid >> 6;
  int lr = lane & 15, hi = lane >> 4;
  int rowbase = blk * 16;
  int batch = rowbase >> 11;
  int row = rowbase + lr;
  f32x4 acc; acc.x = 0.f; acc.y = 0.f; acc.z = 0.f; acc.w = 0.f;
  const float* xrow = x + (size_t)row * 2048 + wv * 512 + hi * 8;
  unsigned short* xbrow = xb + (size_t)row * 2048 + wv * 512 + hi * 8;
  const unsigned short* artrow = Art + ((size_t)batch * 16 + lr) * 2048 + wv * 512 + hi * 8;
  #pragma unroll
  for (int ks = 0; ks < 16; ++ks) {
    f32x4 v0 = *(const f32x4*)(xrow + ks * 32);
    f32x4 v1 = *(const f32x4*)(xrow + ks * 32 + 4);
    bf16x8 av;
    av[0] = (short)f2b(v0.x); av[1] = (short)f2b(v0.y);
    av[2] = (short)f2b(v0.z); av[3] = (short)f2b(v0.w);
    av[4] = (short)f2b(v1.x); av[5] = (short)f2b(v1.y);
    av[6] = (short)f2b(v1.z); av[7] = (short)f2b(v1.w);
    *(bf16x8*)(xbrow + ks * 32) = av;
    bf16x8 bv = *(const bf16x8*)(artrow + ks * 32);
    acc = __builtin_amdgcn_mfma_f32_16x16x32_bf16(av, bv, acc, 0, 0, 0);
  }
  #pragma unroll
  for (int j = 0; j < 4; ++j) red[wv][hi * 4 + j][lr] = acc[j];
  __syncthreads();
  int rr = tid >> 4, cc = tid & 15;
  float s = red[0][rr][cc] + red[1][rr][cc] + red[2][rr][cc] + red[3][rr][cc];
  xa[(size_t)(rowbase + rr) * 16 + cc] = f2b(s);
}

// ---------------- K3: 256x256 GEMM; A via LDS (dbuf 2x32KB), B L2->regs (X/Y banks) ----------------
// 512 threads = 8 waves (2 x 4). Per-wave output 128x64. 16x16x32 MFMA.
// Grid: tn = bid&7 -> each XCD owns ONE 256-col output panel; its 1MB Wb stripe is L2-resident.
//       tm = bid>>3 streams A panels (xb 64MB is L3-resident for cross-XCD reuse).
// LDS/K-tile: 32KB A-write + 128KB A-read = 160KB (~1900 cyc) < MFMA 2048 cyc -> LDS off critical path.
// B: 8 global_load_dwordx4 per wave per K-tile (16 rows x 64B full lines, L2-hit), prefetched
//    one K-tile (~2500 cyc) ahead into alternating reg banks X/Y (2-tile unrolled loop).
// Register budget: acc 128 AGPR + frags a(32)+bX(32)+bY(32)=96 VGPR + addr ~25 -> ~248/256. No spill expected.
//
// vmcnt LEDGER (manual waits for A-stages only; B loads are compiler-dataflow-tracked):
//  per tile issues: ph1: A0'(kt+1)x2, B0n(kt+1)x4; ph2: A1'(kt+1)x2; ph3: B1n(kt+1)x4.
//  ph3-end VMCNT(10): lands A0'(kt+1) [newer = B0n4+A1'2+B1n4=10]; BAR(ph4) publishes -> ph4 rd A0(kt+1) safe.
//  ph4-end VMCNT(4):  lands B0n,A1'(kt+1) [newer = B1n4];          BAR(ph1/ph2) publishes -> ph2 rd A1(kt+1) safe.
//  WAR: each A region staged >=4 barriers after its last read. Prologue VMCNT(8) lands A(0) stages.
__global__ __launch_bounds__(512)
void gemm_kernel(const unsigned short* __restrict__ xb,  // [16384][2048] bf16
                 const unsigned short* __restrict__ Wb,  // [2048][2048]  bf16 (row = out col)
                 const float* __restrict__ bias,         // [2048]
                 const unsigned short* __restrict__ xa,  // [16384][16]   bf16
                 const unsigned short* __restrict__ Brt, // [8][2048][16] bf16 (pre-scaled 1/16)
                 float* __restrict__ out)                // [16384][2048] f32
{
  __shared__ __align__(16) char lds[65536];
  const int tid = threadIdx.x;
  const int lane = tid & 63;
  const int wv = tid >> 6;
  const int wr = wv >> 2, wc = wv & 3;
  const int lr = lane & 15, hi = lane >> 4;
  const int hi16 = hi * 16;

  const int bid = blockIdx.x;
  const int tn = bid & 7, tm = bid >> 3;
  const int rowbase = tm * 256, colbase = tn * 256;

  // A staging geometry (validated R2-R7): thread stages row row0, 16B chunk tid&7, inverse-swizzled src col
  const int row0 = tid >> 3;
  const int scb_e = (((tid & 7) * 16) ^ ((row0 & 7) << 4)) >> 1;

  // B global base: frag (NH, nf, kk) of tile kt at
  //   bgbase + (NH*32 + nf*16)*2048 + kt*64 + kk*32
  const unsigned short* bgbase = Wb + (size_t)(colbase + wc * 64 + lr) * 2048 + hi * 8;

#define GL16(LDSOFF, GPTR) \
  __builtin_amdgcn_global_load_lds((const __attribute__((address_space(1))) unsigned int*)(GPTR), \
      (__attribute__((address_space(3))) unsigned int*)(lds + (LDSOFF)), 16, 0, 0)

#define STAGE_A(MH, DBUF, KOFF) { \
  const unsigned short* g_ = xb + (size_t)(rowbase + (MH)*64 + row0) * 2048 + (KOFF) + scb_e; \
  GL16((DBUF)*32768 + (MH)*16384 + tid*16, g_); \
  GL16((DBUF)*32768 + (MH)*16384 + 8192 + tid*16, g_ + 128*2048); \
}

#define LOADB(BREG, NH, KOFF) \
  _Pragma("unroll") \
  for (int nf = 0; nf < 2; ++nf) \
    _Pragma("unroll") \
    for (int kk = 0; kk < 2; ++kk) \
      BREG[nf][kk] = *(const bf16x8*)(bgbase + ((NH)*32 + nf*16) * 2048 + (KOFF) + kk*32);

#define READ_A(MH, ABASE) \
  _Pragma("unroll") \
  for (int mf = 0; mf < 4; ++mf) { \
    int ar_ = (MH)*128 + wr*64 + mf*16 + lr; \
    _Pragma("unroll") \
    for (int kk = 0; kk < 2; ++kk) \
      a[mf][kk] = *(const bf16x8*)((ABASE) + ar_*128 + ((kk*64 + hi16) ^ ((ar_&7)<<4))); \
  }

#define MM(MH, NH, BREG) \
  __builtin_amdgcn_s_setprio(1); \
  _Pragma("unroll") \
  for (int mf = 0; mf < 4; ++mf) \
    _Pragma("unroll") \
    for (int nf = 0; nf < 2; ++nf) \
      _Pragma("unroll") \
      for (int kk = 0; kk < 2; ++kk) \
        acc[(MH)*4+mf][(NH)*2+nf] = __builtin_amdgcn_mfma_f32_16x16x32_bf16( \
            a[mf][kk], BREG[nf][kk], acc[(MH)*4+mf][(NH)*2+nf], 0, 0, 0); \
  __builtin_amdgcn_s_setprio(0);

// One K-tile, 4 phases. B0C/B1C: this tile's B-frags; B0N/B1N: loaded for tile KT+1.
#define KTILE(KT, B0C, B1C, B0N, B1N) { \
  const int buf_ = (KT) & 1, nbuf_ = buf_ ^ 1; \
  const char* Ab_  = lds + buf_ * 32768; \
  const char* Abn_ = lds + nbuf_ * 32768; \
  const int k1_ = ((KT) + 1) * 64; \
  /* ph1 */ \
  BAR(); \
  if ((KT) < 31) { STAGE_A(0, nbuf_, k1_); LOADB(B0N, 0, k1_); } \
  SBAR0(); \
  MM(0, 0, B0C); \
  /* ph2 */ \
  BAR(); \
  if ((KT) < 31) STAGE_A(1, nbuf_, k1_); \
  SBAR0(); \
  MM(0, 1, B1C); \
  READ_A(1, Ab_); \
  /* ph3 */ \
  BAR(); \
  if ((KT) < 31) LOADB(B1N, 1, k1_); \
  SBAR0(); \
  MM(1, 0, B0C); \
  if ((KT) < 31) { VMCNT(10); } \
  /* ph4 */ \
  BAR(); \
  SBAR0(); \
  MM(1, 1, B1C); \
  if ((KT) < 31) { READ_A(0, Abn_); VMCNT(4); } \
}

  f32x4 acc[8][4];
  #pragma unroll
  for (int i = 0; i < 8; ++i)
    #pragma unroll
    for (int n = 0; n < 4; ++n) { acc[i][n].x = 0.f; acc[i][n].y = 0.f; acc[i][n].z = 0.f; acc[i][n].w = 0.f; }

  bf16x8 a[4][2], bx0[2][2], bx1[2][2], by0[2][2], by1[2][2];

  // Prologue: stage A(0) -> buf0 (4 gloads), load B(0) -> X bank (8 loads).
  // VMCNT(8) lands the A stages (leaves B in flight; compiler waits before first MM).
  STAGE_A(0, 0, 0);
  STAGE_A(1, 0, 0);
  LOADB(bx0, 0, 0);
  LOADB(bx1, 1, 0);
  VMCNT(8);
  BAR();
  READ_A(0, lds);   // a <- A0(0)

  for (int kt2 = 0; kt2 < 32; kt2 += 2) {
    KTILE(kt2,     bx0, bx1, by0, by1);   // uses X, prefetches Y
    KTILE(kt2 + 1, by0, by1, bx0, bx1);   // uses Y, prefetches X
  }

  // ---- LoRA epilogue (validated R3): zero-padded 16x16x32 MFMA per frag ----
  const int batch = rowbase >> 11;
  bf16x8 zf = (bf16x8)(short)0;
  bf16x8 ea[8], eb[4];
  #pragma unroll
  for (int i = 0; i < 8; ++i) {
    if (hi < 2)
      ea[i] = *(const bf16x8*)(xa + (size_t)(rowbase + wr * 128 + i * 16 + lr) * 16 + hi * 8);
    else
      ea[i] = zf;
  }
  #pragma unroll
  for (int n = 0; n < 4; ++n) {
    if (hi < 2)
      eb[n] = *(const bf16x8*)(Brt + ((size_t)batch * 2048 + colbase + wc * 64 + n * 16 + lr) * 16 + hi * 8);
    else
      eb[n] = zf;
  }
  #pragma unroll
  for (int i = 0; i < 8; ++i)
    #pragma unroll
    for (int n = 0; n < 4; ++n)
      acc[i][n] = __builtin_amdgcn_mfma_f32_16x16x32_bf16(ea[i], eb[n], acc[i][n], 0, 0, 0);

  // ---- bias + store (C/D: col = lane&15, row = (lane>>4)*4 + j) ----
  #pragma unroll
  for (int n = 0; n < 4; ++n) {
    int col = colbase + wc * 64 + n * 16 + lr;
    float bbv = bias[col];
    #pragma unroll
    for (int i = 0; i < 8; ++i) {
      int r0 = rowbase + wr * 128 + i * 16 + hi * 4;
      #pragma unroll
      for (int j = 0; j < 4; ++j)
        out[(size_t)(r0 + j) * 2048 + col] = acc[i][n][j] + bbv;
    }
  }
#undef GL16
#undef STAGE_A
#undef LOADB
#undef READ_A
#undef MM
#undef KTILE
}

extern "C" void kernel_launch(void* const* d_in, const int* in_sizes, int n_in,
                              void* d_out, int out_size, void* d_ws, size_t ws_size,
                              hipStream_t stream) {
  const float* x      = (const float*)d_in[0];   // [8][2048][2048]
  const float* W      = (const float*)d_in[1];   // [2048][2048]
  const float* bias   = (const float*)d_in[2];   // [2048]
  const float* logits = (const float*)d_in[3];   // [32][8]
  const float* A      = (const float*)d_in[4];   // [1][8][2048][16]
  const float* B      = (const float*)d_in[5];   // [1][8][16][2048]
  const int*   tasks  = (const int*)d_in[6];     // [8]
  float* out = (float*)d_out;

  char* ws = (char*)d_ws;
  unsigned short* xb  = (unsigned short*)(ws);                         // 67108864 B
  unsigned short* Wb  = (unsigned short*)(ws + 67108864);              //  8388608 B
  unsigned short* xa  = (unsigned short*)(ws + 67108864 + 8388608);    //   524288 B
  unsigned short* Art = (unsigned short*)(ws + 67108864 + 8388608 + 524288);
  unsigned short* Brt = (unsigned short*)(ws + 67108864 + 8388608 + 1048576);

  combine_kernel<<<64, 256, 0, stream>>>(logits, tasks, A, B, Art, Brt);
  prep_kernel<<<1152, 256, 0, stream>>>(x, Art, W, Wb, xb, xa);
  gemm_kernel<<<512, 512, 0, stream>>>(xb, Wb, bias, xa, Brt, out);
}

// Round 9
// 190.914 us; speedup vs baseline: 1.3674x; 1.3674x over previous
//
#include <hip/hip_runtime.h>

typedef __attribute__((ext_vector_type(4))) float f32x4;
typedef __attribute__((ext_vector_type(8))) short bf16x8;

__device__ __forceinline__ unsigned short f2b(float f) {
  unsigned u = __float_as_uint(f);
  u = (u + 0x7FFFu + ((u >> 16) & 1u)) >> 16;
  return (unsigned short)u;
}

#define BAR() asm volatile("s_barrier" ::: "memory")
#define VMCNT(N) asm volatile("s_waitcnt vmcnt(" #N ")" ::: "memory")
#define LGKM0() { asm volatile("s_waitcnt lgkmcnt(0)" ::: "memory"); __builtin_amdgcn_sched_barrier(0); }

// ---------------- K1: selector + skill-mix of LoRA params ----------------
__global__ void combine_kernel(const float* __restrict__ logits,   // [32][8]
                               const int*   __restrict__ tasks,    // [8]
                               const float* __restrict__ A,        // [8][2048][16]
                               const float* __restrict__ B,        // [8][16][2048]
                               unsigned short* __restrict__ Art,   // [8][16][2048]
                               unsigned short* __restrict__ Brt)   // [8][2048][16]
{
  int idx = blockIdx.x * 256 + threadIdx.x;
  int b = idx >> 11;
  int i = idx & 2047;
  if (b >= 8) return;
  int task = tasks[b];
  float p[8]; float s = 0.f;
  #pragma unroll
  for (int t = 0; t < 8; ++t) {
    float l = logits[task * 8 + t];
    float e = 1.f / (1.f + __expf(-l));
    p[t] = e; s += e;
  }
  float inv = 1.f / (s + 1e-12f);
  #pragma unroll
  for (int t = 0; t < 8; ++t) p[t] *= inv;

  float ar[16];
  #pragma unroll
  for (int r = 0; r < 16; ++r) ar[r] = 0.f;
  for (int t = 0; t < 8; ++t) {
    const float* ap = A + ((size_t)t * 2048 + i) * 16;
    float pt = p[t];
    #pragma unroll
    for (int r = 0; r < 16; ++r) ar[r] += pt * ap[r];
  }
  #pragma unroll
  for (int r = 0; r < 16; ++r)
    Art[((size_t)b * 16 + r) * 2048 + i] = f2b(ar[r]);

  float br[16];
  #pragma unroll
  for (int r = 0; r < 16; ++r) br[r] = 0.f;
  for (int t = 0; t < 8; ++t) {
    float pt = p[t];
    #pragma unroll
    for (int r = 0; r < 16; ++r) br[r] += pt * B[((size_t)t * 16 + r) * 2048 + i];
  }
  #pragma unroll
  for (int r = 0; r < 16; ++r)
    Brt[((size_t)b * 2048 + i) * 16 + r] = f2b(br[r] * 0.0625f);
}

// ---------------- K2: prep = {x f32->bf16 + xa = x@A_mix} ∪ {W f32->bf16} ----------------
__global__ void prep_kernel(const float* __restrict__ x,            // [16384][2048]
                            const unsigned short* __restrict__ Art, // [8][16][2048]
                            const float* __restrict__ W,            // [2048][2048]
                            unsigned short* __restrict__ Wb,        // [2048][2048]
                            unsigned short* __restrict__ xb,        // [16384][2048]
                            unsigned short* __restrict__ xa)        // [16384][16]
{
  __shared__ float red[4][16][16];
  int blk = blockIdx.x;
  int tid = threadIdx.x;
  if (blk >= 1024) {
    int idx0 = (blk - 1024) * 256 + tid;
    #pragma unroll
    for (int c = 0; c < 32; ++c) {
      size_t i = ((size_t)idx0 + (size_t)c * 32768) * 4;
      f32x4 v = *(const f32x4*)(W + i);
      ushort4 o;
      o.x = f2b(v.x); o.y = f2b(v.y); o.z = f2b(v.z); o.w = f2b(v.w);
      *(ushort4*)(Wb + i) = o;
    }
    return;
  }
  int lane = tid & 63, wv = tid >> 6;
  int lr = lane & 15, hi = lane >> 4;
  int rowbase = blk * 16;
  int batch = rowbase >> 11;
  int row = rowbase + lr;
  f32x4 acc; acc.x = 0.f; acc.y = 0.f; acc.z = 0.f; acc.w = 0.f;
  const float* xrow = x + (size_t)row * 2048 + wv * 512 + hi * 8;
  unsigned short* xbrow = xb + (size_t)row * 2048 + wv * 512 + hi * 8;
  const unsigned short* artrow = Art + ((size_t)batch * 16 + lr) * 2048 + wv * 512 + hi * 8;
  #pragma unroll
  for (int ks = 0; ks < 16; ++ks) {
    f32x4 v0 = *(const f32x4*)(xrow + ks * 32);
    f32x4 v1 = *(const f32x4*)(xrow + ks * 32 + 4);
    bf16x8 av;
    av[0] = (short)f2b(v0.x); av[1] = (short)f2b(v0.y);
    av[2] = (short)f2b(v0.z); av[3] = (short)f2b(v0.w);
    av[4] = (short)f2b(v1.x); av[5] = (short)f2b(v1.y);
    av[6] = (short)f2b(v1.z); av[7] = (short)f2b(v1.w);
    *(bf16x8*)(xbrow + ks * 32) = av;
    bf16x8 bv = *(const bf16x8*)(artrow + ks * 32);
    acc = __builtin_amdgcn_mfma_f32_16x16x32_bf16(av, bv, acc, 0, 0, 0);
  }
  #pragma unroll
  for (int j = 0; j < 4; ++j) red[wv][hi * 4 + j][lr] = acc[j];
  __syncthreads();
  int rr = tid >> 4, cc = tid & 15;
  float s = red[0][rr][cc] + red[1][rr][cc] + red[2][rr][cc] + red[3][rr][cc];
  xa[(size_t)(rowbase + rr) * 16 + cc] = f2b(s);
}

// ---------------- K3: 256x256 GEMM — faithful m201 8-phase region-interleaved port ----------------
// 512 thr = 8 waves (2 wr x 4 wc); per-wave out 128x64; 16x16x32 MFMA; LDS 128KB.
// Per buf (65536B): A0@0, A1@16384, B0@32768, B1@49152 (each 128 ldsrows x 128B = 16KB).
// Region mapping (strip-permuted so each wave's quadrant rows are contiguous):
//   A half h holds tile rows r with ((r>>6)&1)==h at ldsrow = (r>>7)*64 + (r&63).
//   B half h holds tile cols c with ((c>>5)&1)==h at ldsrow = (c>>6)*32 + (c&31).
// T2 XOR swizzle both-sides: phys colbyte = cb ^ ((ldsrow&7)<<4)  (validated 0-conflict R2-R7).
// Phase plan per iteration (2 K-tiles: even->buf0, odd->buf1); reads 8/4/8/4 per phase;
// ONE half-tile stage (2 gloads) per phase; stage region = region whose last read was prev phase:
//   ph1: rdA0(b0)        stage B0e | ph2: rdB1(b0) stage A0e | ph3: rdA1(b0) stage B1e
//   ph4: stage A1e, VMCNT(6), rdB0(b1) | ph5-8 mirror on buf1 (stages ->odd tile)
// Each phase: {reads; stage} BAR lgkmcnt(0)+schedbar setprio(1) 16xMFMA setprio(0) BAR.
// FIFO ledger (h1..h8 = B0e,A0e,B1e,A1e,B0o,A0o,B1o,A1o; 2 loads each):
//   ph4 VMCNT(6): queue [prev h6,h7,h8 | h1..h4]=14 -> lands prev h6-h8 + h1  => B0e(next) landed
//   ph8 VMCNT(6): queue [h2..h8]... -> keeps {h6,h7,h8}, lands h2..h5          => A0e,B1e,A1e,B0o landed
//   All reads verified >= 1 barrier after land-guarantee; all stages exactly >=1 barrier after last read.
// Prologue: 16 loads (t0: B0,A0,B1,A1 -> buf0; t1: B0,A0,B1,A1 -> buf1); VMCNT(6) keeps {A0o,B1o,A1o}.
// Tail it=15: no stages; ph4 VMCNT(0); ph8 no next-read/vmcnt.
__global__ __launch_bounds__(512, 2)
void gemm_kernel(const unsigned short* __restrict__ xb,  // [16384][2048] bf16
                 const unsigned short* __restrict__ Wb,  // [2048][2048]  bf16 (row = out col)
                 const float* __restrict__ bias,         // [2048]
                 const unsigned short* __restrict__ xa,  // [16384][16]   bf16
                 const unsigned short* __restrict__ Brt, // [8][2048][16] bf16 (pre-scaled 1/16)
                 float* __restrict__ out)                // [16384][2048] f32
{
  __shared__ __align__(16) char lds[131072];
  const int tid = threadIdx.x;
  const int lane = tid & 63;
  const int wv = tid >> 6;
  const int wr = wv >> 2, wc = wv & 3;
  const int lr = lane & 15, hi = lane >> 4;
  const int hi16 = hi * 16;

  const int bid = blockIdx.x;
  const int swz = (bid & 7) * 64 + (bid >> 3);
  const int tm = swz >> 3, tn = swz & 7;
  const int rowbase = tm * 256, colbase = tn * 256;

  // staging geometry: gload g covers chunk c = tid + g*512; ldsrow l = c>>3; colbyte cb=(c&7)*16
  const int l0 = tid >> 3,          cb0 = (tid & 7) * 16;
  const int l1 = (tid + 512) >> 3,  cb1 = ((tid + 512) & 7) * 16;
  const int sc0 = (cb0 ^ ((l0 & 7) << 4)) >> 1;   // inverse-swizzled source col (elements)
  const int sc1 = (cb1 ^ ((l1 & 7) << 4)) >> 1;
  // A source rows for the two gloads of half H: r = (l>>6)*128 + H*64 + (l&63)
  const int arow0 = ((l0 >> 6) << 7) + (l0 & 63);
  const int arow1 = ((l1 >> 6) << 7) + (l1 & 63);
  // B source rows (Wb rows = out cols): c = (l>>5)*64 + H*32 + (l&31)
  const int brow0 = ((l0 >> 5) << 6) + (l0 & 31);
  const int brow1 = ((l1 >> 5) << 6) + (l1 & 31);

#define GL16(LDSOFF, GPTR) \
  __builtin_amdgcn_global_load_lds((const __attribute__((address_space(1))) unsigned int*)(GPTR), \
      (__attribute__((address_space(3))) unsigned int*)(lds + (LDSOFF)), 16, 0, 0)

#define STAGE_A(H, DBUF, KO) { \
  GL16((DBUF)*65536 + (H)*16384 + tid*16, \
       xb + (size_t)(rowbase + arow0 + (H)*64) * 2048 + (KO) + sc0); \
  GL16((DBUF)*65536 + (H)*16384 + 8192 + tid*16, \
       xb + (size_t)(rowbase + arow1 + (H)*64) * 2048 + (KO) + sc1); \
}
#define STAGE_B(H, DBUF, KO) { \
  GL16((DBUF)*65536 + 32768 + (H)*16384 + tid*16, \
       Wb + (size_t)(colbase + brow0 + (H)*32) * 2048 + (KO) + sc0); \
  GL16((DBUF)*65536 + 32768 + (H)*16384 + 8192 + tid*16, \
       Wb + (size_t)(colbase + brow1 + (H)*32) * 2048 + (KO) + sc1); \
}

#define RD_A(H, BUF) \
  _Pragma("unroll") \
  for (int mf = 0; mf < 4; ++mf) { \
    int lrw_ = wr*64 + mf*16 + lr; \
    _Pragma("unroll") \
    for (int kk = 0; kk < 2; ++kk) \
      a[mf][kk] = *(const bf16x8*)(lds + (BUF)*65536 + (H)*16384 + lrw_*128 + \
                                   ((kk*64 + hi16) ^ ((lrw_&7)<<4))); \
  }
#define RD_B(H, BUF, BREG) \
  _Pragma("unroll") \
  for (int nf = 0; nf < 2; ++nf) { \
    int lrw_ = wc*32 + nf*16 + lr; \
    _Pragma("unroll") \
    for (int kk = 0; kk < 2; ++kk) \
      BREG[nf][kk] = *(const bf16x8*)(lds + (BUF)*65536 + 32768 + (H)*16384 + lrw_*128 + \
                                      ((kk*64 + hi16) ^ ((lrw_&7)<<4))); \
  }
#define MM(H, BH, BREG) \
  __builtin_amdgcn_s_setprio(1); \
  _Pragma("unroll") \
  for (int mf = 0; mf < 4; ++mf) \
    _Pragma("unroll") \
    for (int nf = 0; nf < 2; ++nf) \
      _Pragma("unroll") \
      for (int kk = 0; kk < 2; ++kk) \
        acc[(H)*4+mf][(BH)*2+nf] = __builtin_amdgcn_mfma_f32_16x16x32_bf16( \
            a[mf][kk], BREG[nf][kk], acc[(H)*4+mf][(BH)*2+nf], 0, 0, 0); \
  __builtin_amdgcn_s_setprio(0);

  f32x4 acc[8][4];
  #pragma unroll
  for (int i = 0; i < 8; ++i)
    #pragma unroll
    for (int n = 0; n < 4; ++n) { acc[i][n].x = 0.f; acc[i][n].y = 0.f; acc[i][n].z = 0.f; acc[i][n].w = 0.f; }

  bf16x8 a[4][2], b0[2][2], b1[2][2];

  // Prologue (FIFO order = ledger): t0 -> buf0, t1 -> buf1.
  STAGE_B(0, 0, 0);  STAGE_A(0, 0, 0);  STAGE_B(1, 0, 0);  STAGE_A(1, 0, 0);
  STAGE_B(0, 1, 64); STAGE_A(0, 1, 64); STAGE_B(1, 1, 64); STAGE_A(1, 1, 64);
  VMCNT(6);           // lands t0 all + B0(t1); leaves {A0,B1,A1}(t1) = steady invariant
  BAR();
  RD_B(0, 0, b0);     // b0 <- B0(t0); waited by ph1's lgkmcnt(0)

  for (int it = 0; it < 16; ++it) {
    const int koe = (2 * it + 2) * 64, koo = (2 * it + 3) * 64;
    const bool st = (it < 15);

    // ph1: rd A0(buf0); stage B0e
    RD_A(0, 0);
    if (st) STAGE_B(0, 0, koe);
    BAR(); LGKM0();
    MM(0, 0, b0);
    BAR();
    // ph2: rd B1(buf0); stage A0e
    RD_B(1, 0, b1);
    if (st) STAGE_A(0, 0, koe);
    BAR(); LGKM0();
    MM(0, 1, b1);
    BAR();
    // ph3: rd A1(buf0); stage B1e
    RD_A(1, 0);
    if (st) STAGE_B(1, 0, koe);
    BAR(); LGKM0();
    MM(1, 0, b0);
    BAR();
    // ph4: stage A1e; VMCNT(6); rd B0(buf1) [next tile's B0]
    if (st) { STAGE_A(1, 0, koe); VMCNT(6); } else { VMCNT(0); }
    RD_B(0, 1, b0);
    BAR(); LGKM0();
    MM(1, 1, b1);
    BAR();
    // ph5: rd A0(buf1); stage B0o
    RD_A(0, 1);
    if (st) STAGE_B(0, 1, koo);
    BAR(); LGKM0();
    MM(0, 0, b0);
    BAR();
    // ph6: rd B1(buf1); stage A0o
    RD_B(1, 1, b1);
    if (st) STAGE_A(0, 1, koo);
    BAR(); LGKM0();
    MM(0, 1, b1);
    BAR();
    // ph7: rd A1(buf1); stage B1o
    RD_A(1, 1);
    if (st) STAGE_B(1, 1, koo);
    BAR(); LGKM0();
    MM(1, 0, b0);
    BAR();
    // ph8: stage A1o; VMCNT(6); rd B0(buf0) [next even tile's B0]
    if (st) { STAGE_A(1, 1, koo); VMCNT(6); RD_B(0, 0, b0); }
    BAR(); LGKM0();
    MM(1, 1, b1);
    BAR();
  }

  // ---- LoRA epilogue (validated R3): zero-padded 16x16x32 MFMA per frag ----
  // acc row index i = H*4+mf -> tile row = wr*128 + H*64 + mf*16 (+C/D row);  col n -> wc*64 + n*16.
  const int batch = rowbase >> 11;
  bf16x8 zf = (bf16x8)(short)0;
  bf16x8 ea[8], eb[4];
  #pragma unroll
  for (int i = 0; i < 8; ++i) {
    int trow = wr * 128 + (i >> 2) * 64 + (i & 3) * 16 + lr;
    if (hi < 2)
      ea[i] = *(const bf16x8*)(xa + (size_t)(rowbase + trow) * 16 + hi * 8);
    else
      ea[i] = zf;
  }
  #pragma unroll
  for (int n = 0; n < 4; ++n) {
    int tcol = wc * 64 + (n >> 1) * 32 + (n & 1) * 16 + lr;
    if (hi < 2)
      eb[n] = *(const bf16x8*)(Brt + ((size_t)batch * 2048 + colbase + tcol) * 16 + hi * 8);
    else
      eb[n] = zf;
  }
  #pragma unroll
  for (int i = 0; i < 8; ++i)
    #pragma unroll
    for (int n = 0; n < 4; ++n)
      acc[i][n] = __builtin_amdgcn_mfma_f32_16x16x32_bf16(ea[i], eb[n], acc[i][n], 0, 0, 0);

  // ---- bias + store (C/D: col = lane&15, row = (lane>>4)*4 + j) ----
  #pragma unroll
  for (int n = 0; n < 4; ++n) {
    int col = colbase + wc * 64 + (n >> 1) * 32 + (n & 1) * 16 + lr;
    float bbv = bias[col];
    #pragma unroll
    for (int i = 0; i < 8; ++i) {
      int r0 = rowbase + wr * 128 + (i >> 2) * 64 + (i & 3) * 16 + hi * 4;
      #pragma unroll
      for (int j = 0; j < 4; ++j)
        out[(size_t)(r0 + j) * 2048 + col] = acc[i][n][j] + bbv;
    }
  }
#undef GL16
#undef STAGE_A
#undef STAGE_B
#undef RD_A
#undef RD_B
#undef MM
}

extern "C" void kernel_launch(void* const* d_in, const int* in_sizes, int n_in,
                              void* d_out, int out_size, void* d_ws, size_t ws_size,
                              hipStream_t stream) {
  const float* x      = (const float*)d_in[0];   // [8][2048][2048]
  const float* W      = (const float*)d_in[1];   // [2048][2048]
  const float* bias   = (const float*)d_in[2];   // [2048]
  const float* logits = (const float*)d_in[3];   // [32][8]
  const float* A      = (const float*)d_in[4];   // [1][8][2048][16]
  const float* B      = (const float*)d_in[5];   // [1][8][16][2048]
  const int*   tasks  = (const int*)d_in[6];     // [8]
  float* out = (float*)d_out;

  char* ws = (char*)d_ws;
  unsigned short* xb  = (unsigned short*)(ws);                         // 67108864 B
  unsigned short* Wb  = (unsigned short*)(ws + 67108864);              //  8388608 B
  unsigned short* xa  = (unsigned short*)(ws + 67108864 + 8388608);    //   524288 B
  unsigned short* Art = (unsigned short*)(ws + 67108864 + 8388608 + 524288);
  unsigned short* Brt = (unsigned short*)(ws + 67108864 + 8388608 + 1048576);

  combine_kernel<<<64, 256, 0, stream>>>(logits, tasks, A, B, Art, Brt);
  prep_kernel<<<1152, 256, 0, stream>>>(x, Art, W, Wb, xb, xa);
  gemm_kernel<<<512, 512, 0, stream>>>(xb, Wb, bias, xa, Brt, out);
}